// Round 4
// baseline (29.671 us; speedup 1.0000x reference)
//
#include <hip/hip_runtime.h>

#define DIM 10
#define BATCH 65536

typedef float v2f __attribute__((ext_vector_type(2)));

static __device__ __forceinline__ v2f vfma2(v2f a, v2f b, v2f c) {
    return __builtin_elementwise_fma(a, b, c);
}
static __device__ __forceinline__ v2f vmax2(v2f a, v2f b) {
    return __builtin_elementwise_max(a, b);
}

// 2 threads per batch element: lane 2k -> channels 0..5, lane 2k+1 -> channels
// 6..9 + 2 zero-pad channels. Identical instruction stream, per-lane weights.
// acc pair-reduced via __shfl_xor(...,1) (register-only). 2 waves/SIMD.
__launch_bounds__(256, 2)
__global__ void net_kernel(const float* __restrict__ x,
                           const float* __restrict__ w1,
                           const float* __restrict__ b1,
                           const float* __restrict__ w2,
                           const float* __restrict__ b2,
                           const float* __restrict__ fc1_w,
                           const float* __restrict__ fc1_b,
                           const float* __restrict__ fc2_w,
                           const float* __restrict__ fc2_b,
                           float* __restrict__ out) {
    // 128 elements x 100 floats = 51.2 KiB (linear: global_load_lds needs
    // contiguous wave-uniform-base + lane*16 destinations).
    __shared__ __align__(16) float xs[128 * DIM * DIM];

    const int tid  = threadIdx.x;
    const int wave = tid >> 6;
    const int lane = tid & 63;
    const int half = tid & 1;        // which channel half this lane owns
    const int eloc = tid >> 1;       // element index within block [0,128)
    const size_t eglob0 = (size_t)blockIdx.x * 128;

    // ---- Phase 1: coalesced global -> LDS staging (50 chunks of 1 KiB) ----
    const float* gbase = x + eglob0 * (DIM * DIM);
    #pragma unroll
    for (int i = 0; i < 13; ++i) {
        const int c = wave * 13 + i;          // waves 0..2: 13 chunks, wave 3: 11
        if (c < 50) {
            __builtin_amdgcn_global_load_lds(
                (const __attribute__((address_space(1))) void*)(gbase + c * 256 + lane * 4),
                (__attribute__((address_space(3))) void*)(xs + c * 256),
                16, 0, 0);
        }
    }

    // ---- per-lane weights (6 channels, branchless pad) while loads fly ----
    v2f W1p[3], B1p[3], W2p[3][9];
    #pragma unroll
    for (int cp = 0; cp < 3; ++cp) {
        const int c0 = half * 6 + 2 * cp, c1 = c0 + 1;
        const int s0 = (c0 < 10) ? c0 : 0, s1 = (c1 < 10) ? c1 : 0;  // safe idx
        const float w1a = (c0 < 10) ? w1[s0] : 0.0f;
        const float w1b = (c1 < 10) ? w1[s1] : 0.0f;
        const float b1a = (c0 < 10) ? b1[s0] : -1.0f;   // g = max(-1,0) = 0
        const float b1b = (c1 < 10) ? b1[s1] : -1.0f;
        W1p[cp] = (v2f){w1a, w1b};
        B1p[cp] = (v2f){b1a, b1b};
        #pragma unroll
        for (int k = 0; k < 9; ++k) {
            const float wa = (c0 < 10) ? w2[s0 * 9 + k] : 0.0f;
            const float wb = (c1 < 10) ? w2[s1 * 9 + k] : 0.0f;
            W2p[cp][k] = (v2f){wa, wb};
        }
    }
    const float B2 = b2[0];

    __syncthreads();

    // ---- Phase 2: row/col sums from LDS (both lanes of a pair read the
    //      same element -> pairwise broadcast; 4-way conflict across pairs) ----
    float row[DIM], col[DIM];
    #pragma unroll
    for (int i = 0; i < DIM; ++i) { row[i] = 0.f; col[i] = 0.f; }
    const float4* xb = reinterpret_cast<const float4*>(xs + eloc * (DIM * DIM));
    #pragma unroll
    for (int t = 0; t < 25; ++t) {
        const float4 v = xb[t];
        const int e0 = t * 4;
        row[(e0 + 0) / DIM] += v.x; col[(e0 + 0) % DIM] += v.x;
        row[(e0 + 1) / DIM] += v.y; col[(e0 + 1) % DIM] += v.y;
        row[(e0 + 2) / DIM] += v.z; col[(e0 + 2) % DIM] += v.z;
        row[(e0 + 3) / DIM] += v.w; col[(e0 + 3) % DIM] += v.w;
    }

    // ---- Phase 3: 55 lower-triangle pixels, 6 channels (3 v2f) per lane ----
    float acc[DIM][DIM];
    #pragma unroll
    for (int i = 0; i < DIM; ++i)
        #pragma unroll
        for (int j = 0; j < DIM; ++j) acc[i][j] = 0.f;

    #pragma unroll
    for (int p = 0; p < DIM; ++p) {
        #pragma unroll
        for (int q = 0; q <= p; ++q) {
            const float e = row[p] + col[q];
            const v2f e2 = (v2f){e, e};
            v2f s2[9];
            #pragma unroll
            for (int k = 0; k < 9; ++k) s2[k] = (v2f){0.f, 0.f};
            #pragma unroll
            for (int cp = 0; cp < 3; ++cp) {
                const v2f g = vmax2(vfma2(W1p[cp], e2, B1p[cp]), (v2f){0.f, 0.f});
                #pragma unroll
                for (int k = 0; k < 9; ++k) s2[k] = vfma2(g, W2p[cp][k], s2[k]);
            }
            float s[9];
            #pragma unroll
            for (int k = 0; k < 9; ++k) s[k] = s2[k][0] + s2[k][1];
            // scatter: source (p,q) feeds out (p+1-a, q+1-bb), tap k=a*3+bb
            #pragma unroll
            for (int a = 0; a < 3; ++a) {
                const int i = p + 1 - a;
                if (i < 0 || i >= DIM) continue;          // folds at compile time
                #pragma unroll
                for (int bb = 0; bb < 3; ++bb) {
                    const int j = q + 1 - bb;
                    if (j < 0 || j >= DIM) continue;
                    acc[i][j] += s[a * 3 + bb];
                }
            }
        }
    }

    // ---- Phase 4: pair butterfly reduce (register-only, no barrier) ----
    #pragma unroll
    for (int i = 0; i < DIM; ++i)
        #pragma unroll
        for (int j = 0; j < DIM; ++j)
            acc[i][j] += __shfl_xor(acc[i][j], 1, 64);

    // ---- m = relu(acc + b2); v[k] = row-sum + col-sum (both lanes, redundant) ----
    float vsum[DIM];
    #pragma unroll
    for (int k = 0; k < DIM; ++k) vsum[k] = 0.f;
    #pragma unroll
    for (int i = 0; i < DIM; ++i) {
        #pragma unroll
        for (int j = 0; j < DIM; ++j) {
            const float m = fmaxf(acc[i][j] + B2, 0.f);
            vsum[i] += m;
            vsum[j] += m;
        }
    }

    // ---- FC head ----
    float hid[4];
    #pragma unroll
    for (int t = 0; t < 4; ++t) {
        float a = fc1_b[t];
        #pragma unroll
        for (int k = 0; k < DIM; ++k) a = fmaf(vsum[k], fc1_w[t * DIM + k], a);
        hid[t] = fmaxf(a, 0.f);
    }
    float o0 = fc2_b[0], o1 = fc2_b[1];
    #pragma unroll
    for (int t = 0; t < 4; ++t) {
        o0 = fmaf(hid[t], fc2_w[t], o0);
        o1 = fmaf(hid[t], fc2_w[4 + t], o1);
    }

    // even lane stores .x, odd lane stores .y -> fully coalesced float stores
    const float val = half ? o1 : o0;
    out[eglob0 * 2 + tid] = val;   // == &out[(eglob0+eloc)*2 + half]
}

extern "C" void kernel_launch(void* const* d_in, const int* in_sizes, int n_in,
                              void* d_out, int out_size, void* d_ws, size_t ws_size,
                              hipStream_t stream) {
    const float* x     = (const float*)d_in[0];
    const float* w1    = (const float*)d_in[1];
    const float* b1    = (const float*)d_in[2];
    const float* w2    = (const float*)d_in[3];
    const float* b2    = (const float*)d_in[4];
    const float* fc1_w = (const float*)d_in[5];
    const float* fc1_b = (const float*)d_in[6];
    const float* fc2_w = (const float*)d_in[7];
    const float* fc2_b = (const float*)d_in[8];
    float* out = (float*)d_out;

    const int block = 256;                    // 128 elements per block
    const int grid = (BATCH * 2) / block;     // 512 blocks, 2 per CU
    net_kernel<<<grid, block, 0, stream>>>(x, w1, b1, w2, b2, fc1_w, fc1_b,
                                           fc2_w, fc2_b, out);
}